// Round 4
// baseline (160.165 us; speedup 1.0000x reference)
//
#include <hip/hip_runtime.h>
#include <math.h>

#define NFFT    800
#define HOP     200
#define NB      32
#define TLEN    480000
#define NFRAMES 2401
#define PAD     400

#define TW      4000            // output span per block
#define NBLK_T  (TLEN / TW)     // 120
#define NFRLOC  23              // frames touching a TW span
#define NSEG    20              // 200-sample hop segments per block

// Analytic collapse of STFT->mag/phase->iSTFT:
//   out[p] = 0.75*x[t] + A'(seg,par) - R'(seg,par)*cos(2*pi*p/800 - psi)
// where (A',R',psi) derive from the 4 covering frames' even/odd windowed
// sums E_f,O_f. No LDS staging of x: block working set (20.8 KB) fits L1.
__global__ __launch_bounds__(256) void stft_fused(const float* __restrict__ x,
                                                  const float* __restrict__ win,
                                                  float* __restrict__ out) {
    __shared__ float2 eo[NFRLOC];
    __shared__ float4 segc[2][NSEG];   // [parity][seg] = (A', R', psi, _)

    const int blk = blockIdx.x;
    const int b   = blk / NBLK_T;
    const int bt  = blk - b * NBLK_T;
    const int t0  = bt * TW;
    const int fbase = t0 / HOP - 1;
    const float* xb = x + (size_t)b * TLEN;
    const int wave = threadIdx.x >> 6;
    const int lane = threadIdx.x & 63;
    const bool fast = (bt >= 1) && (bt <= NBLK_T - 2);  // block-uniform

    if (fast) {
        // window fragments straight into registers (global, coalesced, L2-hot)
        const float4* wv4 = (const float4*)win;
        const float4 w0 = wv4[lane];
        const float4 w1 = wv4[lane + 64];
        const float4 w2 = wv4[lane + 128];
        const float4 w3 = (lane < 8) ? wv4[lane + 192] : make_float4(0.f, 0.f, 0.f, 0.f);

        // per-frame even/odd windowed sums from global (L1 absorbs 4x overlap)
        const float* xf = xb + t0 - 600;    // frame li starts at xf + 200*li (16B aligned)
        for (int li = wave; li < NFRLOC; li += 4) {
            const float4* xv4 = (const float4*)(xf + HOP * li);
            float ae = 0.f, ao = 0.f;
            float4 v;
            v = xv4[lane];       ae += w0.x * v.x + w0.z * v.z;  ao += w0.y * v.y + w0.w * v.w;
            v = xv4[lane + 64];  ae += w1.x * v.x + w1.z * v.z;  ao += w1.y * v.y + w1.w * v.w;
            v = xv4[lane + 128]; ae += w2.x * v.x + w2.z * v.z;  ao += w2.y * v.y + w2.w * v.w;
            if (lane < 8) {
                v = xv4[lane + 192];
                ae += w3.x * v.x + w3.z * v.z;  ao += w3.y * v.y + w3.w * v.w;
            }
            for (int m = 1; m < 64; m <<= 1) { ae += __shfl_xor(ae, m); ao += __shfl_xor(ao, m); }
            if (lane == 0) eo[li] = make_float2(ae, ao);
        }
        __syncthreads();

        // per-segment trig constants (40 threads)
        if (threadIdx.x < 2 * NSEG) {
            const int par = threadIdx.x & 1;
            const int s   = threadIdx.x >> 1;
            float A = 0.f, C = 0.f, D = 0.f;
#pragma unroll
            for (int k = 0; k < 4; ++k) {
                const int li = s + k;
                const int f  = fbase + li;
                const float2 v = eo[li];
                const float  S = par ? v.y : v.x;
                const int fm = f & 3;
                A += S;
                C += (fm == 0) ? S : ((fm == 2) ? -S : 0.f);
                D += (fm == 1) ? S : ((fm == 3) ? -S : 0.f);
            }
            segc[par][s] = make_float4(A * (1.0f / 1600.0f),
                                       sqrtf(C * C + D * D) * (1.0f / 1600.0f),
                                       atan2f(D, C), 0.f);
        }
        __syncthreads();

        // synth: stream x from global (L1-hot), trig form, float4 stores
        const float4* xg4  = (const float4*)(xb + t0);
        float4* outb4 = (float4*)(out + (size_t)b * TLEN + t0);
        const float delta = 6.28318530717958647692f / 800.0f;
        for (int j4 = threadIdx.x; j4 < TW / 4; j4 += 256) {
            const float4 xv = xg4[j4];
            const int s = j4 / 50;
            const float4 ce = segc[0][s];
            const float4 co = segc[1][s];
            const int pm0 = (400 + 4 * j4) % 800;   // p mod 800 (t0 % 800 == 0)
            const float xa[4] = {xv.x, xv.y, xv.z, xv.w};
            float r[4];
#pragma unroll
            for (int c = 0; c < 4; ++c) {
                const float4 cc = (c & 1) ? co : ce;
                const float ang = (float)(pm0 + c) * delta - cc.z;
                r[c] = 0.75f * xa[c] + cc.x - cc.y * __cosf(ang);
            }
            outb4[j4] = make_float4(r[0], r[1], r[2], r[3]);
        }
    } else {
        // boundary blocks (bt==0 / bt==119): scalar clamped loads, general loop
        for (int li = wave; li < NFRLOC; li += 4) {
            const int f = fbase + li;
            float a = 0.f;
            if (f >= 0 && f < NFRAMES) {
                const int base = f * HOP - PAD;
                for (int n = lane; n < NFFT; n += 64) {   // n parity == lane parity
                    int t = base + n;
                    t = min(max(t, 0), TLEN - 1);
                    a += win[n] * xb[t];
                }
            }
            // parity-preserving butterfly (skip mask 1): even lanes->E, odd->O
            for (int m = 2; m < 64; m <<= 1) a += __shfl_xor(a, m);
            const float e = __shfl(a, 0);
            const float o = __shfl(a, 1);
            if (lane == 0) eo[li] = make_float2(e, o);
        }
        __syncthreads();

        const float4* xg4  = (const float4*)(xb + t0);
        float4* outb4 = (float4*)(out + (size_t)b * TLEN + t0);
        for (int j4 = threadIdx.x; j4 < TW / 4; j4 += 256) {
            const float4 xv = xg4[j4];
            const float xa[4] = {xv.x, xv.y, xv.z, xv.w};
            float r[4];
            const int pbase = t0 + 4 * j4 + PAD;
#pragma unroll
            for (int c = 0; c < 4; ++c) {
                const int p = pbase + c;
                int fhi = p / HOP;
                if (fhi > NFRAMES - 1) fhi = NFRAMES - 1;
                const int flo = (p >= NFFT) ? (p - NFFT) / HOP + 1 : 0;
                const bool odd = (p & 1) != 0;
                float acc = 0.f;
                for (int f = flo; f <= fhi; ++f) {
                    const int n = p - HOP * f;
                    const float w = win[n];
                    const float2 s2 = eo[f - fbase];
                    acc += w * (0.5f * w * xa[c] + (1.0f / 800.0f) * (odd ? s2.y : s2.x));
                }
                r[c] = acc;
            }
            outb4[j4] = make_float4(r[0], r[1], r[2], r[3]);
        }
    }
}

extern "C" void kernel_launch(void* const* d_in, const int* in_sizes, int n_in,
                              void* d_out, int out_size, void* d_ws, size_t ws_size,
                              hipStream_t stream) {
    const float* x   = (const float*)d_in[0];
    const float* wfr = (const float*)d_in[1];   // (401, 800); row 0 = hann window
    float* out = (float*)d_out;

    stft_fused<<<dim3(NB * NBLK_T), dim3(256), 0, stream>>>(x, wfr, out);
}

// Round 5
// 144.867 us; speedup vs baseline: 1.1056x; 1.1056x over previous
//
#include <hip/hip_runtime.h>
#include <math.h>

#define NFFT    800
#define HOP     200
#define NB      32
#define TLEN    480000
#define NFRAMES 2401
#define NSEGG   2404          // segments g in [-2, 2401] (incl. edge-pad segments)
#define QPB     16            // output segments per synth block
#define NQB     (TLEN / HOP / QPB)   // 150

#define DLT  0.00785398163397448f    // 2*pi/800
// cos/sin of k*DLT for k=1..3 (angle-addition within a float4 chunk)
#define C1K  0.99996915760f
#define S1K  0.00785390090f
#define C2K  0.99987663248f
#define S2K  0.01570731731f
#define C3K  0.99972243010f
#define S3K  0.02355976470f

// Analytic collapse (validated rounds 1-4):
//   out[p] = 0.75*x[t] + A'(q,par) - R'(q,par)*cos(2*pi*p/800 - psi)
// with (A,C,D) built from frame sums S_f(par), and
//   w[n] = 0.5 + 0.5*(cos(pi*f/2)*c(t) + sin(pi*f/2)*s(t)),  c/s = cos/sin(2*pi*t/800)
// so S_f(par) = sum_{g=f-2}^{f+1} [0.5*P1 + 0.5*(cosphi*Pc + sinphi*Ps)](g,par)
// where P1,Pc,Ps are per-segment basis partials of raw x. x is read exactly once in K1.

// K1: one wave per segment -> 6 partials (P1e,P1o,Pce,Pco,Pse,Pso)
__global__ __launch_bounds__(256) void seg_partials(const float* __restrict__ x,
                                                    float* __restrict__ P) {
    const int wave = threadIdx.x >> 6;
    const int lane = threadIdx.x & 63;
    const int sg = blockIdx.x * 4 + wave;        // [0, NB*NSEGG)
    const int b  = sg / NSEGG;
    const int g  = sg - b * NSEGG - 2;           // [-2, 2401]
    const float* xb = x + (size_t)b * TLEN;

    float p1e = 0.f, p1o = 0.f, pce = 0.f, pco = 0.f, pse = 0.f, pso = 0.f;
    if (lane < 50) {
        float4 v;
        if (g >= 0 && g <= 2399) {
            v = ((const float4*)(xb + 200 * g))[lane];     // 16B-aligned, coalesced
        } else {
            const float xv = (g < 0) ? xb[0] : xb[TLEN - 1];  // edge-pad segments
            v = make_float4(xv, xv, xv, xv);
        }
        const int gm = (g + 4) & 3;              // t mod 800 phase (200g even always)
        const int tm = gm * 200 + 4 * lane;      // virtual t mod 800 for v.x
        float s0, c0;
        __sincosf((float)tm * DLT, &s0, &c0);
        const float c1 = c0 * C1K - s0 * S1K, s1 = s0 * C1K + c0 * S1K;
        const float c2 = c0 * C2K - s0 * S2K, s2 = s0 * C2K + c0 * S2K;
        const float c3 = c0 * C3K - s0 * S3K, s3 = s0 * C3K + c0 * S3K;
        p1e = v.x + v.z;            p1o = v.y + v.w;
        pce = c0 * v.x + c2 * v.z;  pco = c1 * v.y + c3 * v.w;
        pse = s0 * v.x + s2 * v.z;  pso = s1 * v.y + s3 * v.w;
    }
    for (int m = 1; m < 64; m <<= 1) {
        p1e += __shfl_xor(p1e, m);  p1o += __shfl_xor(p1o, m);
        pce += __shfl_xor(pce, m);  pco += __shfl_xor(pco, m);
        pse += __shfl_xor(pse, m);  pso += __shfl_xor(pso, m);
    }
    if (lane == 0) {
        float* r = P + (size_t)sg * 6;           // 24B records, 8B-aligned
        ((float2*)r)[0] = make_float2(p1e, p1o);
        ((float2*)r)[1] = make_float2(pce, pco);
        ((float2*)r)[2] = make_float2(pse, pso);
    }
}

// K2: per block, rebuild per-segment (A',R',psi) from partials, then stream synth.
__global__ __launch_bounds__(256) void synth(const float* __restrict__ x,
                                             const float* __restrict__ P,
                                             float* __restrict__ out) {
    __shared__ float  stage[22 * 6];         // partials for g in [q0-3, q0+18]
    __shared__ float4 segc[2][QPB];          // [parity][q-q0] = (A', R', psi, _)
    __shared__ float  sfs[2][19];            // slow path: S_f for f in [q0-1, q0+17]

    const int qb = blockIdx.x;               // [0, NQB)
    const int b  = blockIdx.y;
    const int q0 = qb * QPB;

    if (threadIdx.x < 22 * 6) {
        int g = q0 - 3 + (int)(threadIdx.x / 6);
        g = min(max(g, -2), 2401);           // clamp only matters for boundary blocks
        stage[threadIdx.x] = P[(size_t)(b * NSEGG + g + 2) * 6 + threadIdx.x % 6];
    }
    __syncthreads();

    const bool slowb = (qb == 0) || (qb == NQB - 1);

    if (!slowb) {
        if (threadIdx.x < 2 * QPB) {
            const int par = threadIdx.x & 1;
            const int ql  = threadIdx.x >> 1;
            const int q   = q0 + ql;
            float A = 0.f, C = 0.f, D = 0.f;
            for (int f = q - 1; f <= q + 2; ++f) {
                const int s0i = (f - 2) - (q0 - 3);
                float sp1 = 0.f, spc = 0.f, sps = 0.f;
#pragma unroll
                for (int k = 0; k < 4; ++k) {
                    const float* rec = &stage[(s0i + k) * 6];
                    sp1 += rec[par];  spc += rec[2 + par];  sps += rec[4 + par];
                }
                const int fm = f & 3;
                const float tr = (fm == 0) ? spc : (fm == 1) ? sps : (fm == 2) ? -spc : -sps;
                const float S = 0.5f * sp1 + 0.5f * tr;
                A += S;
                if (fm == 0) C += S; else if (fm == 2) C -= S;
                else if (fm == 1) D += S; else D -= S;
            }
            segc[par][ql] = make_float4(A * (1.0f / 1600.0f),
                                        sqrtf(C * C + D * D) * (1.0f / 1600.0f),
                                        atan2f(D, C), 0.f);
        }
        __syncthreads();

        const float4* xg4 = (const float4*)(x + (size_t)b * TLEN + HOP * q0);
        float4* og4 = (float4*)(out + (size_t)b * TLEN + HOP * q0);
        const int pmb = (q0 & 3) * 200 + 400;
        for (int j = threadIdx.x; j < 50 * QPB; j += 256) {
            const float4 xv = xg4[j];
            const int sl = j / 50;
            const float4 ce = segc[0][sl];
            const float4 co = segc[1][sl];
            const int pm = (pmb + 4 * j) % 800;
            const float xa[4] = {xv.x, xv.y, xv.z, xv.w};
            float r[4];
#pragma unroll
            for (int c = 0; c < 4; ++c) {
                const float4 cc = (c & 1) ? co : ce;
                r[c] = 0.75f * xa[c] + cc.x - cc.y * __cosf((float)(pm + c) * DLT - cc.z);
            }
            og4[j] = make_float4(r[0], r[1], r[2], r[3]);
        }
    } else {
        // boundary blocks: build S_f table, general per-sample frame loop
        if (threadIdx.x < 38) {
            const int par = threadIdx.x & 1;
            const int fl  = threadIdx.x >> 1;
            const int f   = q0 - 1 + fl;
            float S = 0.f;
            if (f >= 0 && f < NFRAMES) {
                const int s0i = (f - 2) - (q0 - 3);
                float sp1 = 0.f, spc = 0.f, sps = 0.f;
#pragma unroll
                for (int k = 0; k < 4; ++k) {
                    const float* rec = &stage[(s0i + k) * 6];
                    sp1 += rec[par];  spc += rec[2 + par];  sps += rec[4 + par];
                }
                const int fm = f & 3;
                const float tr = (fm == 0) ? spc : (fm == 1) ? sps : (fm == 2) ? -spc : -sps;
                S = 0.5f * sp1 + 0.5f * tr;
            }
            sfs[par][fl] = S;
        }
        __syncthreads();

        const float4* xg4 = (const float4*)(x + (size_t)b * TLEN + HOP * q0);
        float4* og4 = (float4*)(out + (size_t)b * TLEN + HOP * q0);
        for (int j = threadIdx.x; j < 50 * QPB; j += 256) {
            const float4 xv = xg4[j];
            const float xa[4] = {xv.x, xv.y, xv.z, xv.w};
            float r[4];
            const int pbase = HOP * q0 + 4 * j + 400;
#pragma unroll
            for (int c = 0; c < 4; ++c) {
                const int p = pbase + c;
                int fhi = p / HOP;
                if (fhi > NFRAMES - 1) fhi = NFRAMES - 1;
                const int flo = (p >= NFFT) ? (p - NFFT) / HOP + 1 : 0;
                const int par = p & 1;
                float acc = 0.f;
                for (int f = flo; f <= fhi; ++f) {
                    const int n = p - HOP * f;
                    const float w = 0.5f - 0.5f * __cosf((float)n * DLT);
                    acc += w * (0.5f * w * xa[c] + (1.0f / 800.0f) * sfs[par][f - (q0 - 1)]);
                }
                r[c] = acc;
            }
            og4[j] = make_float4(r[0], r[1], r[2], r[3]);
        }
    }
}

extern "C" void kernel_launch(void* const* d_in, const int* in_sizes, int n_in,
                              void* d_out, int out_size, void* d_ws, size_t ws_size,
                              hipStream_t stream) {
    const float* x = (const float*)d_in[0];
    float* out = (float*)d_out;
    float* P   = (float*)d_ws;    // NB*NSEGG*6 floats = 1,846,272 B

    seg_partials<<<dim3(NB * NSEGG / 4), dim3(256), 0, stream>>>(x, P);
    synth<<<dim3(NQB, NB), dim3(256), 0, stream>>>(x, P, out);
}

// Round 6
// 122.683 us; speedup vs baseline: 1.3055x; 1.1808x over previous
//
#include <hip/hip_runtime.h>
#include <math.h>

#define HOP     200
#define NB      32
#define TLEN    480000
#define QPB     16                     // output segments per block
#define NQB     (TLEN / HOP / QPB)     // 150
#define NSEGP   22                     // partial segments per block: [q0-3, q0+18]

#define DLT  0.00785398163397448f      // 2*pi/800
// cos/sin of k*DLT, k=1..3 (within-float4 angle stepping)
#define C1K  0.99996915760f
#define S1K  0.00785390090f
#define C2K  0.99987663248f
#define S2K  0.01570731731f
#define C3K  0.99972243010f
#define S3K  0.02355976470f
// rotation by 40*DLT = pi/10 (between a thread's successive float4s)
#define C40  0.95105651629515f
#define S40  0.30901699437495f

// Analytic collapse (validated R1-R5):
//   out[p] = 0.75*x[t] + A'(q,par) - R'(q,par)*cos(p*DLT - psi)  [+ edge w^2 corr]
// built from per-segment basis partials P1,Pc,Ps (x read once), via
//   w[n] = 0.5 + 0.5*(cos(pi*f/2)*cos(t*DLT) + sin(pi*f/2)*sin(t*DLT))
// Boundary frames (f<0 / f>2400) are masked in (A,C,D); the missing w^2*x
// term on the first/last 200 samples of each row is added analytically.
__global__ __launch_bounds__(256) void stft_one(const float* __restrict__ x,
                                                float* __restrict__ out) {
    __shared__ float  part[NSEGP][10][6];  // per-(segment, sub-thread) partials
    __shared__ float  pg[NSEGP][6];        // per-segment partials
    __shared__ float4 segc[2][QPB];        // [parity][q-q0] = (A', R', psi, _)

    const int qb = blockIdx.x;             // [0, NQB)
    const int b  = blockIdx.y;
    const int q0 = qb * QPB;
    const float* xb = x + (size_t)b * TLEN;

    // ---- Phase A: register-accumulated basis partials, no shuffles ----
    if (threadIdx.x < NSEGP * 10) {
        const int s = threadIdx.x / 10;    // local segment
        const int k = threadIdx.x - 10 * s;
        const int g = q0 - 3 + s;          // global segment in [-3, 2402]
        const int gm = (g + 4) & 3;        // virtual t mod 800 phase
        float c0, s0;
        __sincosf((float)(gm * 200 + 4 * k) * DLT, &s0, &c0);
        float p1e = 0.f, p1o = 0.f, pce = 0.f, pco = 0.f, pse = 0.f, pso = 0.f;
        const bool inb = (g >= 0) && (g <= 2399);
        float4 ve;
        if (!inb) {                        // edge-pad segment: constant x
            const float xe = (g < 0) ? xb[0] : xb[TLEN - 1];
            ve = make_float4(xe, xe, xe, xe);
        }
#pragma unroll
        for (int i = 0; i < 5; ++i) {
            float4 v;
            if (inb) v = ((const float4*)(xb + 200 * g))[k + 10 * i];
            else     v = ve;
            const float c1 = c0 * C1K - s0 * S1K, s1 = s0 * C1K + c0 * S1K;
            const float c2 = c0 * C2K - s0 * S2K, s2 = s0 * C2K + c0 * S2K;
            const float c3 = c0 * C3K - s0 * S3K, s3 = s0 * C3K + c0 * S3K;
            p1e += v.x + v.z;            p1o += v.y + v.w;
            pce += c0 * v.x + c2 * v.z;  pco += c1 * v.y + c3 * v.w;
            pse += s0 * v.x + s2 * v.z;  pso += s1 * v.y + s3 * v.w;
            const float cn = c0 * C40 - s0 * S40;   // advance 40 samples
            s0 = s0 * C40 + c0 * S40;  c0 = cn;
        }
        part[s][k][0] = p1e;  part[s][k][1] = p1o;
        part[s][k][2] = pce;  part[s][k][3] = pco;
        part[s][k][4] = pse;  part[s][k][5] = pso;
    }
    __syncthreads();

    // ---- Phase B: fold 10 sub-partials per segment ----
    if (threadIdx.x < NSEGP * 6) {
        const int s = threadIdx.x / 6;
        const int c = threadIdx.x - 6 * s;
        float a = 0.f;
#pragma unroll
        for (int k = 0; k < 10; ++k) a += part[s][k][c];
        pg[s][c] = a;
    }
    __syncthreads();

    // ---- Phase C: per-(segment,parity) trig constants, masked frames ----
    if (threadIdx.x < 2 * QPB) {
        const int par = threadIdx.x & 1;
        const int ql  = threadIdx.x >> 1;
        const int q   = q0 + ql;
        float A = 0.f, C = 0.f, D = 0.f;
#pragma unroll
        for (int df = -1; df <= 2; ++df) {
            const int f = q + df;
            if (f < 0 || f > 2400) continue;      // boundary frame mask
            const int ls0 = f - q0 + 1;           // local index of g=f-2
            float sp1 = 0.f, spc = 0.f, sps = 0.f;
#pragma unroll
            for (int kk = 0; kk < 4; ++kk) {
                const float* rec = pg[ls0 + kk];
                sp1 += rec[par];  spc += rec[2 + par];  sps += rec[4 + par];
            }
            const int fm = f & 3;
            const float tr = (fm == 0) ? spc : (fm == 1) ? sps : (fm == 2) ? -spc : -sps;
            const float S = 0.5f * sp1 + 0.5f * tr;
            A += S;
            if (fm == 0) C += S; else if (fm == 2) C -= S;
            else if (fm == 1) D += S; else D -= S;
        }
        segc[par][ql] = make_float4(A * (1.0f / 1600.0f),
                                    sqrtf(C * C + D * D) * (1.0f / 1600.0f),
                                    atan2f(D, C), 0.f);
    }
    __syncthreads();

    // ---- Phase D: stream synth (x re-read is L1-hot from Phase A) ----
    const bool headblk = (qb == 0);
    const bool tailblk = (qb == NQB - 1);
    const float4* xg4 = (const float4*)(xb + HOP * q0);
    float4* og4 = (float4*)(out + (size_t)b * TLEN + HOP * q0);
    const int pmb = (q0 & 3) * 200 + 400;
    for (int j = threadIdx.x; j < 50 * QPB; j += 256) {
        const float4 xv = xg4[j];
        const int sl = j / 50;
        const float4 ce = segc[0][sl];
        const float4 co = segc[1][sl];
        const int pm = (pmb + 4 * j) % 800;
        const float xa[4] = {xv.x, xv.y, xv.z, xv.w};
        float r[4];
#pragma unroll
        for (int c = 0; c < 4; ++c) {
            const float4 cc = (c & 1) ? co : ce;
            r[c] = 0.75f * xa[c] + cc.x - cc.y * __cosf((float)(pm + c) * DLT - cc.z);
        }
        // first/last segment of the row: subtract the invalid frame's w^2 term
        if (headblk && sl == 0) {
#pragma unroll
            for (int c = 0; c < 4; ++c) {
                const float wm = 0.5f + 0.5f * __sinf((float)(pm + c) * DLT);
                r[c] -= 0.5f * wm * wm * xa[c];
            }
        }
        if (tailblk && sl == QPB - 1) {
#pragma unroll
            for (int c = 0; c < 4; ++c) {
                const float wm = 0.5f - 0.5f * __sinf((float)(pm + c) * DLT);
                r[c] -= 0.5f * wm * wm * xa[c];
            }
        }
        og4[j] = make_float4(r[0], r[1], r[2], r[3]);
    }
}

extern "C" void kernel_launch(void* const* d_in, const int* in_sizes, int n_in,
                              void* d_out, int out_size, void* d_ws, size_t ws_size,
                              hipStream_t stream) {
    const float* x = (const float*)d_in[0];
    float* out = (float*)d_out;
    stft_one<<<dim3(NQB, NB), dim3(256), 0, stream>>>(x, out);
}